// Round 8
// baseline (219.413 us; speedup 1.0000x reference)
//
#include <hip/hip_runtime.h>
#include <hip/hip_bf16.h>

// ---------------------------------------------------------------------------
// Fused attention block, bf16 MFMA pipeline.
//   x[2,2048,1024] -> qkv GEMM (+bias, fused per-head LN on q,k) -> flash attn
//   -> proj GEMM (+bias) -> out fp32.
// MFMA 16x16x32 bf16 layouts:
//   A: lane l holds row (l&15), k = 8*(l>>4)+e
//   B: lane l holds col (l&15), k = 8*(l>>4)+e
//   C/D: lane l holds col (l&15), row = (l>>4)*4 + reg
//
// R8 = R6 structure + attn XCD swizzle only.
// R7 post-mortem: counted-vmcnt + dual s_barrier per K-step REGRESSED the
// 2-phase GEMM (66->93us) — the R6 stage-early single-__syncthreads loop
// already overlaps loads with MFMA compute; the extra barrier is pure cost
// (matches guide: T4 pays only in 8-phase schedules, negative on 2-phase).
// The attn XCD swizzle (each XCD owns 4 bh -> 2MB K/V L2-resident) was the
// win hiding in R7's flat total — kept here, isolated.
// ---------------------------------------------------------------------------

typedef short bf16x8 __attribute__((ext_vector_type(8)));
typedef float f32x4  __attribute__((ext_vector_type(4)));

__device__ __forceinline__ short f2bf(float f) {
  union { float f; unsigned u; } c; c.f = f;
  unsigned r = c.u + 0x7fffu + ((c.u >> 16) & 1u);   // RNE
  return (short)(r >> 16);
}

// pack two f32 -> two bf16 in one u32 (lo = a, hi = b), RNE
__device__ __forceinline__ unsigned pk2(float a, float b) {
  __hip_bfloat162 h = __float22bfloat162_rn(make_float2(a, b));
  unsigned u;
  __builtin_memcpy(&u, &h, 4);
  return u;
}

__device__ __forceinline__ void gld16(const void* g, void* l) {
  __builtin_amdgcn_global_load_lds(
      (const __attribute__((address_space(1))) unsigned int*)(unsigned long long)g,
      (__attribute__((address_space(3))) unsigned int*)(unsigned int)(unsigned long long)l,
      16, 0, 0);
}

// ---------------------------------------------------------------------------
__global__ void k_cvt(const float* __restrict__ in, short* __restrict__ out, int n) {
  int i = (blockIdx.x * blockDim.x + threadIdx.x) * 4;
  if (i < n) {
    float4 f = *(const float4*)(in + i);
    uint2 u;
    u.x = pk2(f.x, f.y);
    u.y = pk2(f.z, f.w);
    *(uint2*)(out + i) = u;
  }
}

__global__ void k_transpose(const float* __restrict__ in, short* __restrict__ out,
                            int R, int C) {
  __shared__ float t[32][33];
  const int tx = threadIdx.x, ty = threadIdx.y;
  const int c0 = blockIdx.x * 32, r0 = blockIdx.y * 32;
#pragma unroll
  for (int i = 0; i < 4; i++)
    t[ty * 4 + i][tx] = in[(size_t)(r0 + ty * 4 + i) * C + c0 + tx];
  __syncthreads();
#pragma unroll
  for (int i = 0; i < 4; i++)
    out[(size_t)(c0 + ty * 4 + i) * R + r0 + tx] = f2bf(t[tx][ty * 4 + i]);
}

// ---------------------------------------------------------------------------
// GEMM mainloop: C128x128 = A[M,K]bf16 @ B[N,K]bf16^T.
// 2-phase double-buffered, stage-early, ONE __syncthreads per K-tile
// (R6-proven; do not add extra barriers — R7 regression).
__device__ __forceinline__ void mm_loop(const short* __restrict__ A,
                                        const short* __restrict__ B,
                                        int K, int mBase, int nBase,
                                        short* As, short* Bs, f32x4 acc[4][4]) {
  const int tid = threadIdx.x;
  const int w = tid >> 6, lane = tid & 63;
  const int wr = w >> 1, wc = w & 1;
  const int lhi = lane >> 4, llo = lane & 15;
  const int rin = lane >> 3;
  const int kin = (lane & 7) * 8;

  const f32x4 fz = {0.f, 0.f, 0.f, 0.f};
#pragma unroll
  for (int mi = 0; mi < 4; mi++)
#pragma unroll
    for (int ni = 0; ni < 4; ni++) acc[mi][ni] = fz;

  const int nkt = K >> 6;

  const short* pA[4];
  const short* pB[4];
#pragma unroll
  for (int i = 0; i < 4; i++) {
    const int row = (w * 4 + i) * 8 + rin;
    pA[i] = A + (size_t)(mBase + row) * K + kin;
    pB[i] = B + (size_t)(nBase + row) * K + kin;
  }

#define MMSTAGE(buf)                                                           \
  {                                                                            \
    _Pragma("unroll")                                                          \
    for (int i = 0; i < 4; i++) {                                              \
      const int c = w * 4 + i;                                                 \
      gld16(pA[i], As + (buf) * 8192 + c * 512);                               \
      gld16(pB[i], Bs + (buf) * 8192 + c * 512);                               \
      pA[i] += 64;                                                             \
      pB[i] += 64;                                                             \
    }                                                                          \
  }

  MMSTAGE(0);
  __syncthreads();
  int cur = 0;

  for (int kb = 0; kb < nkt; kb++) {
    if (kb + 1 < nkt) MMSTAGE(cur ^ 1);
    const short* Ac = As + cur * 8192;
    const short* Bc = Bs + cur * 8192;
#pragma unroll
    for (int kk = 0; kk < 2; kk++) {
      bf16x8 a[4], b[4];
#pragma unroll
      for (int mi = 0; mi < 4; mi++)
        a[mi] = *(const bf16x8*)(Ac + (wr * 64 + mi * 16 + llo) * 64 + kk * 32 + lhi * 8);
#pragma unroll
      for (int ni = 0; ni < 4; ni++)
        b[ni] = *(const bf16x8*)(Bc + (wc * 64 + ni * 16 + llo) * 64 + kk * 32 + lhi * 8);
#pragma unroll
      for (int mi = 0; mi < 4; mi++)
#pragma unroll
        for (int ni = 0; ni < 4; ni++)
          acc[mi][ni] = __builtin_amdgcn_mfma_f32_16x16x32_bf16(a[mi], b[ni], acc[mi][ni], 0, 0, 0);
    }
    __syncthreads();
    cur ^= 1;
  }
#undef MMSTAGE
}

// ---------------------------------------------------------------------------
// GEMM1: qkv = x @ w_qkv + b, fused per-head LN epilogue.
__global__ __launch_bounds__(256) void k_gemm_qkv(
    const short* __restrict__ A, const short* __restrict__ B,
    const float* __restrict__ bqkv,
    const float* __restrict__ g_q, const float* __restrict__ be_q,
    const float* __restrict__ g_k, const float* __restrict__ be_k,
    short* __restrict__ Qg, short* __restrict__ Kg, short* __restrict__ Vtg) {
  __shared__ short As[2 * 8192];
  __shared__ short Bs[2 * 8192];
  f32x4 acc[4][4];
  const int mBase = blockIdx.x * 128, nBase = blockIdx.y * 128;
  mm_loop(A, B, 1024, mBase, nBase, As, Bs, acc);

  const int tid = threadIdx.x;
  const int w = tid >> 6, lane = tid & 63;
  const int wr = w >> 1, wc = w & 1;
  const int lhi = lane >> 4, llo = lane & 15;

  const int cg0 = nBase + wc * 64;
  const int t = cg0 >> 10;               // 0=q 1=k 2=v
  const int h = (cg0 & 1023) >> 6;

  float bias[4], gg[4], bb[4];
#pragma unroll
  for (int ni = 0; ni < 4; ni++) {
    const int d = ni * 16 + llo;
    bias[ni] = bqkv[cg0 + d];
    if (t == 0)      { gg[ni] = g_q[d]; bb[ni] = be_q[d]; }
    else if (t == 1) { gg[ni] = g_k[d]; bb[ni] = be_k[d]; }
    else             { gg[ni] = 1.f;    bb[ni] = 0.f; }
  }

#pragma unroll
  for (int mi = 0; mi < 4; mi++) {
    float v[4][4];
#pragma unroll
    for (int ni = 0; ni < 4; ni++)
#pragma unroll
      for (int j = 0; j < 4; j++) v[ni][j] = acc[mi][ni][j] + bias[ni];

    if (t < 2) {
#pragma unroll
      for (int j = 0; j < 4; j++) {
        float s = 0.f, s2 = 0.f;
#pragma unroll
        for (int ni = 0; ni < 4; ni++) { s += v[ni][j]; s2 += v[ni][j] * v[ni][j]; }
#pragma unroll
        for (int msk = 1; msk < 16; msk <<= 1) {
          s  += __shfl_xor(s,  msk, 64);
          s2 += __shfl_xor(s2, msk, 64);
        }
        const float mu = s * 0.015625f;
        const float var = s2 * 0.015625f - mu * mu;
        const float rs = rsqrtf(var + 1e-5f);
#pragma unroll
        for (int ni = 0; ni < 4; ni++) {
          float y = (v[ni][j] - mu) * rs * gg[ni] + bb[ni];
          if (t == 0) y *= 0.125f;       // hd^-0.5
          v[ni][j] = y;
        }
      }
    }
    const int rbase = mBase + wr * 64 + mi * 16 + lhi * 4;
#pragma unroll
    for (int j = 0; j < 4; j++) {
      const int r = rbase + j;
      const int b_ = r >> 11;
      const int n = r & 2047;
      const int bh = b_ * 16 + h;
#pragma unroll
      for (int np = 0; np < 2; np++) {           // ni pairs (0,1) and (2,3)
        const int d0 = np * 32 + llo;
        const unsigned u = pk2(v[np * 2][j], v[np * 2 + 1][j]);
        const short lo = (short)(u & 0xffffu);
        const short hi = (short)(u >> 16);
        if (t == 0) {
          Qg[((size_t)bh * 2048 + n) * 64 + d0]      = lo;
          Qg[((size_t)bh * 2048 + n) * 64 + d0 + 16] = hi;
        } else if (t == 1) {
          Kg[((size_t)bh * 2048 + n) * 64 + d0]      = lo;
          Kg[((size_t)bh * 2048 + n) * 64 + d0 + 16] = hi;
        } else {
          Vtg[((size_t)bh * 64 + d0) * 2048 + n]        = lo;
          Vtg[((size_t)bh * 64 + d0 + 16) * 2048 + n]   = hi;
        }
      }
    }
  }
}

// ---------------------------------------------------------------------------
// Flash attention: swapped QK^T, no-max softmax, packed b64 P-store,
// swizzled LDS, stage-early dbuf (single __syncthreads), XCD-swizzled grid.
__global__ __launch_bounds__(256) void k_attn(const short* __restrict__ Qg,
                                              const short* __restrict__ Kg,
                                              const short* __restrict__ Vtg,
                                              short* __restrict__ aout) {
  __shared__ short KV[2][8192];     // [buf][ K: 0..4095 | V: 4096..8191 ]
  __shared__ short Ps[4][1024];     // per-wave [16 q][64 k], swizzled
  const int tid = threadIdx.x;
  const int w = tid >> 6, lane = tid & 63;
  const int lhi = lane >> 4, llo = lane & 15;
  const int rin = lane >> 3;               // 0..7: row within 8-row chunk
  const int tg = (lane & 7) ^ rin;         // pre-swizzled 16B slot in source

  // XCD swizzle: 1024 blocks = 8 XCDs x 128; XCD k owns bh in [4k, 4k+4)
  // so its K/V working set (4 x 512KB) is L2-resident.
  const int b = blockIdx.x;
  const int w2 = (b & 7) * 128 + (b >> 3);
  const int bh = w2 >> 5;
  const int qrow0 = (w2 & 31) * 64 + w * 16;

  const short* Qrow = Qg + ((size_t)bh * 2048 + qrow0 + llo) * 64;
  const bf16x8 qa0 = *(const bf16x8*)(Qrow + lhi * 8);
  const bf16x8 qa1 = *(const bf16x8*)(Qrow + 32 + lhi * 8);

  bf16x8 onesb;
#pragma unroll
  for (int e = 0; e < 8; e++) onesb[e] = (short)0x3F80;   // bf16 1.0

  const f32x4 fz = {0.f, 0.f, 0.f, 0.f};
  f32x4 o[4];
#pragma unroll
  for (int dg = 0; dg < 4; dg++) o[dg] = fz;
  f32x4 lsum = fz;

  short* Pw = Ps[w];
  const size_t kbase = (size_t)bh * 2048;
  const size_t vbase = (size_t)bh * 64;

  // staging pointers: waves 0,1 load K chunks (advance 64 rows * 64 = 4096),
  // waves 2,3 load V^T chunks (advance 64 cols = 64).
  const short* gp[4];
#pragma unroll
  for (int i = 0; i < 4; i++) {
    const int cc = w * 4 + i;
    gp[i] = (cc < 8)
        ? (Kg  + (kbase + (size_t)(cc * 8 + rin)) * 64 + tg * 8)
        : (Vtg + (vbase + (size_t)((cc - 8) * 8 + rin)) * 2048 + tg * 8);
  }
  const int gstride = (w < 2) ? 4096 : 64;

#define STAGE(buf)                                                             \
  {                                                                            \
    _Pragma("unroll")                                                          \
    for (int i = 0; i < 4; i++) {                                              \
      gld16(gp[i], &KV[buf][(w * 4 + i) * 512]);                               \
      gp[i] += gstride;                                                        \
    }                                                                          \
  }

  STAGE(0);
  __syncthreads();
  int cur = 0;

  for (int kt = 0; kt < 32; kt++) {
    if (kt < 31) STAGE(cur ^ 1);

    const short* Kc = KV[cur];
    const short* Vc = KV[cur] + 4096;

    // S^T[64 k x 16 q] = K @ Q^T  (swapped operands; frag layouts identical)
    // => lane holds S[q=llo][k = krg*16 + lhi*4 + j]
    f32x4 s[4];
    __builtin_amdgcn_s_setprio(1);
#pragma unroll
    for (int krg = 0; krg < 4; krg++) {
      const int rk = krg * 16 + llo;
      const int sw = rk & 7;
      const bf16x8 kb0 = *(const bf16x8*)(Kc + rk * 64 + ((lhi ^ sw)) * 8);
      const bf16x8 kb1 = *(const bf16x8*)(Kc + rk * 64 + (((4 + lhi) ^ sw)) * 8);
      f32x4 z = fz;
      z = __builtin_amdgcn_mfma_f32_16x16x32_bf16(kb0, qa0, z, 0, 0, 0);
      z = __builtin_amdgcn_mfma_f32_16x16x32_bf16(kb1, qa1, z, 0, 0, 0);
      s[krg] = z;
    }
    __builtin_amdgcn_s_setprio(0);

    // P = exp(S); pack 4 consecutive-k bf16 (RNE pk2), ds_write_b64 per krg.
#pragma unroll
    for (int krg = 0; krg < 4; krg++) {
      const float p0 = __expf(s[krg][0]);
      const float p1 = __expf(s[krg][1]);
      const float p2 = __expf(s[krg][2]);
      const float p3 = __expf(s[krg][3]);
      uint2 u;
      u.x = pk2(p0, p1);
      u.y = pk2(p2, p3);
      // byte addr: row llo, k = krg*16 + lhi*4 ; slot = k>>3, swizzled
      char* pb = (char*)Pw + llo * 128 +
                 (((krg * 2 + (lhi >> 1)) ^ (llo & 7)) << 4) + ((lhi & 1) << 3);
      *(uint2*)pb = u;
    }

    // P fragments (A-layout): row=llo, swizzle-read
    const int swp = llo & 7;
    const bf16x8 pa0 = *(const bf16x8*)(Pw + llo * 64 + ((lhi ^ swp)) * 8);
    const bf16x8 pa1 = *(const bf16x8*)(Pw + llo * 64 + (((4 + lhi) ^ swp)) * 8);

    __builtin_amdgcn_s_setprio(1);
    // row sums via MFMA with ones-B (each col of C gets the full row sum)
    lsum = __builtin_amdgcn_mfma_f32_16x16x32_bf16(pa0, onesb, lsum, 0, 0, 0);
    lsum = __builtin_amdgcn_mfma_f32_16x16x32_bf16(pa1, onesb, lsum, 0, 0, 0);

    // O += P @ V   (V^T tile, swizzle-read)
#pragma unroll
    for (int dg = 0; dg < 4; dg++) {
      const int rv = dg * 16 + llo;
      const int swv = rv & 7;
      const bf16x8 vb0 = *(const bf16x8*)(Vc + rv * 64 + ((lhi ^ swv)) * 8);
      const bf16x8 vb1 = *(const bf16x8*)(Vc + rv * 64 + (((4 + lhi) ^ swv)) * 8);
      o[dg] = __builtin_amdgcn_mfma_f32_16x16x32_bf16(pa0, vb0, o[dg], 0, 0, 0);
      o[dg] = __builtin_amdgcn_mfma_f32_16x16x32_bf16(pa1, vb1, o[dg], 0, 0, 0);
    }
    __builtin_amdgcn_s_setprio(0);
    __syncthreads();
    cur ^= 1;
  }
#undef STAGE

  const int b_ = bh >> 4, h = bh & 15;
#pragma unroll
  for (int j = 0; j < 4; j++) {
    const float inv = 1.f / lsum[j];
    const int n = qrow0 + lhi * 4 + j;
    short* arow = aout + ((size_t)(b_ * 2048 + n)) * 1024 + h * 64 + llo;
#pragma unroll
    for (int dp = 0; dp < 2; dp++) {            // dg pairs (0,1), (2,3)
      const unsigned u = pk2(o[dp * 2][j] * inv, o[dp * 2 + 1][j] * inv);
      arow[dp * 32]      = (short)(u & 0xffffu);
      arow[dp * 32 + 16] = (short)(u >> 16);
    }
  }
}

// ---------------------------------------------------------------------------
// GEMM2: out = aout @ w_proj + b_proj  (fp32 output)
__global__ __launch_bounds__(256) void k_gemm_proj(const short* __restrict__ A,
                                                   const short* __restrict__ B,
                                                   const float* __restrict__ bias,
                                                   float* __restrict__ C) {
  __shared__ short As[2 * 8192];
  __shared__ short Bs[2 * 8192];
  f32x4 acc[4][4];
  const int mBase = blockIdx.x * 128, nBase = blockIdx.y * 128;
  mm_loop(A, B, 1024, mBase, nBase, As, Bs, acc);

  const int tid = threadIdx.x;
  const int w = tid >> 6, lane = tid & 63;
  const int wr = w >> 1, wc = w & 1;
  const int lhi = lane >> 4, llo = lane & 15;
#pragma unroll
  for (int mi = 0; mi < 4; mi++)
#pragma unroll
    for (int ni = 0; ni < 4; ni++) {
      const int col = nBase + wc * 64 + ni * 16 + llo;
      const float bv = bias[col];
#pragma unroll
      for (int j = 0; j < 4; j++) {
        const int row = mBase + wr * 64 + mi * 16 + lhi * 4 + j;
        C[(size_t)row * 1024 + col] = acc[mi][ni][j] + bv;
      }
    }
}

// ---------------------------------------------------------------------------
extern "C" void kernel_launch(void* const* d_in, const int* in_sizes, int n_in,
                              void* d_out, int out_size, void* d_ws, size_t ws_size,
                              hipStream_t stream) {
  const float* x      = (const float*)d_in[0];
  const float* w_qkv  = (const float*)d_in[1];
  const float* b_qkv  = (const float*)d_in[2];
  const float* g_q    = (const float*)d_in[3];
  const float* be_q   = (const float*)d_in[4];
  const float* g_k    = (const float*)d_in[5];
  const float* be_k   = (const float*)d_in[6];
  const float* w_proj = (const float*)d_in[7];
  const float* b_proj = (const float*)d_in[8];
  float* out = (float*)d_out;

  char* ws = (char*)d_ws;
  short* xb     = (short*)(ws);                       // 4096x1024      8 MB
  short* wqkvT  = (short*)(ws + ((size_t)8  << 20));  // 3072x1024      6 MB
  short* wprojT = (short*)(ws + ((size_t)14 << 20));  // 1024x1024      2 MB
  short* Qg     = (short*)(ws + ((size_t)16 << 20));  // [32][2048][64] 8 MB
  short* Kg     = (short*)(ws + ((size_t)24 << 20));  // [32][2048][64] 8 MB
  short* Vtg    = (short*)(ws + ((size_t)32 << 20));  // [32][64][2048] 8 MB
  short* aout   = (short*)(ws + ((size_t)40 << 20));  // 4096x1024      8 MB

  k_cvt<<<4096, 256, 0, stream>>>(x, xb, 4096 * 1024);
  k_transpose<<<dim3(3072 / 32, 1024 / 32), dim3(32, 8), 0, stream>>>(w_qkv, wqkvT, 1024, 3072);
  k_transpose<<<dim3(1024 / 32, 1024 / 32), dim3(32, 8), 0, stream>>>(w_proj, wprojT, 1024, 1024);
  k_gemm_qkv<<<dim3(32, 24), 256, 0, stream>>>(xb, wqkvT, b_qkv, g_q, be_q, g_k, be_k, Qg, Kg, Vtg);
  k_attn<<<1024, 256, 0, stream>>>(Qg, Kg, Vtg, aout);
  k_gemm_proj<<<dim3(32, 8), 256, 0, stream>>>(aout, wprojT, b_proj, out);
}

// Round 9
// 219.037 us; speedup vs baseline: 1.0017x; 1.0017x over previous
//
#include <hip/hip_runtime.h>
#include <hip/hip_bf16.h>

// ---------------------------------------------------------------------------
// Fused attention block, bf16 MFMA pipeline.
//   x[2,2048,1024] -> qkv GEMM (+bias, fused per-head LN on q,k) -> flash attn
//   -> proj GEMM (+bias) -> out fp32.
// MFMA 16x16x32 bf16 layouts:
//   A: lane l holds row (l&15), k = 8*(l>>4)+e
//   B: lane l holds col (l&15), k = 8*(l>>4)+e
//   C/D: lane l holds col (l&15), row = (l>>4)*4 + reg
//
// R9 structure attribution (R6/R7/R8 A/B/A):
//  * GEMM mm_loop: stage-early + single __syncthreads (R6 form). Adding
//    counted-vmcnt + dual s_barrier + sched_barrier REGRESSED it 62->93us
//    (R7) — sched_barrier(0) order-pinning in an MFMA-dense loop.
//  * k_attn: counted vmcnt(4) + dual s_barrier (R7 form). The single
//    __syncthreads drains vmcnt(0) INCLUDING the just-issued next-tile
//    stage; attn's short MFMA phase can't hide it (R6/R8 = 65.5us, R7
//    inferred ~35-50us). XCD swizzle kept: FETCH 69.7->12.3MB (R8).
// ---------------------------------------------------------------------------

typedef short bf16x8 __attribute__((ext_vector_type(8)));
typedef float f32x4  __attribute__((ext_vector_type(4)));

__device__ __forceinline__ short f2bf(float f) {
  union { float f; unsigned u; } c; c.f = f;
  unsigned r = c.u + 0x7fffu + ((c.u >> 16) & 1u);   // RNE
  return (short)(r >> 16);
}

// pack two f32 -> two bf16 in one u32 (lo = a, hi = b), RNE
__device__ __forceinline__ unsigned pk2(float a, float b) {
  __hip_bfloat162 h = __float22bfloat162_rn(make_float2(a, b));
  unsigned u;
  __builtin_memcpy(&u, &h, 4);
  return u;
}

__device__ __forceinline__ void gld16(const void* g, void* l) {
  __builtin_amdgcn_global_load_lds(
      (const __attribute__((address_space(1))) unsigned int*)(unsigned long long)g,
      (__attribute__((address_space(3))) unsigned int*)(unsigned int)(unsigned long long)l,
      16, 0, 0);
}

// ---------------------------------------------------------------------------
__global__ void k_cvt(const float* __restrict__ in, short* __restrict__ out, int n) {
  int i = (blockIdx.x * blockDim.x + threadIdx.x) * 4;
  if (i < n) {
    float4 f = *(const float4*)(in + i);
    uint2 u;
    u.x = pk2(f.x, f.y);
    u.y = pk2(f.z, f.w);
    *(uint2*)(out + i) = u;
  }
}

__global__ void k_transpose(const float* __restrict__ in, short* __restrict__ out,
                            int R, int C) {
  __shared__ float t[32][33];
  const int tx = threadIdx.x, ty = threadIdx.y;
  const int c0 = blockIdx.x * 32, r0 = blockIdx.y * 32;
#pragma unroll
  for (int i = 0; i < 4; i++)
    t[ty * 4 + i][tx] = in[(size_t)(r0 + ty * 4 + i) * C + c0 + tx];
  __syncthreads();
#pragma unroll
  for (int i = 0; i < 4; i++)
    out[(size_t)(c0 + ty * 4 + i) * R + r0 + tx] = f2bf(t[tx][ty * 4 + i]);
}

// ---------------------------------------------------------------------------
// GEMM mainloop: C128x128 = A[M,K]bf16 @ B[N,K]bf16^T.
// 2-phase double-buffered, stage-early, ONE __syncthreads per K-tile
// (R6-proven; do not add extra barriers/sched_barrier — R7 regression).
__device__ __forceinline__ void mm_loop(const short* __restrict__ A,
                                        const short* __restrict__ B,
                                        int K, int mBase, int nBase,
                                        short* As, short* Bs, f32x4 acc[4][4]) {
  const int tid = threadIdx.x;
  const int w = tid >> 6, lane = tid & 63;
  const int wr = w >> 1, wc = w & 1;
  const int lhi = lane >> 4, llo = lane & 15;
  const int rin = lane >> 3;
  const int kin = (lane & 7) * 8;

  const f32x4 fz = {0.f, 0.f, 0.f, 0.f};
#pragma unroll
  for (int mi = 0; mi < 4; mi++)
#pragma unroll
    for (int ni = 0; ni < 4; ni++) acc[mi][ni] = fz;

  const int nkt = K >> 6;

  const short* pA[4];
  const short* pB[4];
#pragma unroll
  for (int i = 0; i < 4; i++) {
    const int row = (w * 4 + i) * 8 + rin;
    pA[i] = A + (size_t)(mBase + row) * K + kin;
    pB[i] = B + (size_t)(nBase + row) * K + kin;
  }

#define MMSTAGE(buf)                                                           \
  {                                                                            \
    _Pragma("unroll")                                                          \
    for (int i = 0; i < 4; i++) {                                              \
      const int c = w * 4 + i;                                                 \
      gld16(pA[i], As + (buf) * 8192 + c * 512);                               \
      gld16(pB[i], Bs + (buf) * 8192 + c * 512);                               \
      pA[i] += 64;                                                             \
      pB[i] += 64;                                                             \
    }                                                                          \
  }

  MMSTAGE(0);
  __syncthreads();
  int cur = 0;

  for (int kb = 0; kb < nkt; kb++) {
    if (kb + 1 < nkt) MMSTAGE(cur ^ 1);
    const short* Ac = As + cur * 8192;
    const short* Bc = Bs + cur * 8192;
#pragma unroll
    for (int kk = 0; kk < 2; kk++) {
      bf16x8 a[4], b[4];
#pragma unroll
      for (int mi = 0; mi < 4; mi++)
        a[mi] = *(const bf16x8*)(Ac + (wr * 64 + mi * 16 + llo) * 64 + kk * 32 + lhi * 8);
#pragma unroll
      for (int ni = 0; ni < 4; ni++)
        b[ni] = *(const bf16x8*)(Bc + (wc * 64 + ni * 16 + llo) * 64 + kk * 32 + lhi * 8);
#pragma unroll
      for (int mi = 0; mi < 4; mi++)
#pragma unroll
        for (int ni = 0; ni < 4; ni++)
          acc[mi][ni] = __builtin_amdgcn_mfma_f32_16x16x32_bf16(a[mi], b[ni], acc[mi][ni], 0, 0, 0);
    }
    __syncthreads();
    cur ^= 1;
  }
#undef MMSTAGE
}

// ---------------------------------------------------------------------------
// GEMM1: qkv = x @ w_qkv + b, fused per-head LN epilogue.
__global__ __launch_bounds__(256) void k_gemm_qkv(
    const short* __restrict__ A, const short* __restrict__ B,
    const float* __restrict__ bqkv,
    const float* __restrict__ g_q, const float* __restrict__ be_q,
    const float* __restrict__ g_k, const float* __restrict__ be_k,
    short* __restrict__ Qg, short* __restrict__ Kg, short* __restrict__ Vtg) {
  __shared__ short As[2 * 8192];
  __shared__ short Bs[2 * 8192];
  f32x4 acc[4][4];
  const int mBase = blockIdx.x * 128, nBase = blockIdx.y * 128;
  mm_loop(A, B, 1024, mBase, nBase, As, Bs, acc);

  const int tid = threadIdx.x;
  const int w = tid >> 6, lane = tid & 63;
  const int wr = w >> 1, wc = w & 1;
  const int lhi = lane >> 4, llo = lane & 15;

  const int cg0 = nBase + wc * 64;
  const int t = cg0 >> 10;               // 0=q 1=k 2=v
  const int h = (cg0 & 1023) >> 6;

  float bias[4], gg[4], bb[4];
#pragma unroll
  for (int ni = 0; ni < 4; ni++) {
    const int d = ni * 16 + llo;
    bias[ni] = bqkv[cg0 + d];
    if (t == 0)      { gg[ni] = g_q[d]; bb[ni] = be_q[d]; }
    else if (t == 1) { gg[ni] = g_k[d]; bb[ni] = be_k[d]; }
    else             { gg[ni] = 1.f;    bb[ni] = 0.f; }
  }

#pragma unroll
  for (int mi = 0; mi < 4; mi++) {
    float v[4][4];
#pragma unroll
    for (int ni = 0; ni < 4; ni++)
#pragma unroll
      for (int j = 0; j < 4; j++) v[ni][j] = acc[mi][ni][j] + bias[ni];

    if (t < 2) {
#pragma unroll
      for (int j = 0; j < 4; j++) {
        float s = 0.f, s2 = 0.f;
#pragma unroll
        for (int ni = 0; ni < 4; ni++) { s += v[ni][j]; s2 += v[ni][j] * v[ni][j]; }
#pragma unroll
        for (int msk = 1; msk < 16; msk <<= 1) {
          s  += __shfl_xor(s,  msk, 64);
          s2 += __shfl_xor(s2, msk, 64);
        }
        const float mu = s * 0.015625f;
        const float var = s2 * 0.015625f - mu * mu;
        const float rs = rsqrtf(var + 1e-5f);
#pragma unroll
        for (int ni = 0; ni < 4; ni++) {
          float y = (v[ni][j] - mu) * rs * gg[ni] + bb[ni];
          if (t == 0) y *= 0.125f;       // hd^-0.5
          v[ni][j] = y;
        }
      }
    }
    const int rbase = mBase + wr * 64 + mi * 16 + lhi * 4;
#pragma unroll
    for (int j = 0; j < 4; j++) {
      const int r = rbase + j;
      const int b_ = r >> 11;
      const int n = r & 2047;
      const int bh = b_ * 16 + h;
#pragma unroll
      for (int np = 0; np < 2; np++) {           // ni pairs (0,1) and (2,3)
        const int d0 = np * 32 + llo;
        const unsigned u = pk2(v[np * 2][j], v[np * 2 + 1][j]);
        const short lo = (short)(u & 0xffffu);
        const short hi = (short)(u >> 16);
        if (t == 0) {
          Qg[((size_t)bh * 2048 + n) * 64 + d0]      = lo;
          Qg[((size_t)bh * 2048 + n) * 64 + d0 + 16] = hi;
        } else if (t == 1) {
          Kg[((size_t)bh * 2048 + n) * 64 + d0]      = lo;
          Kg[((size_t)bh * 2048 + n) * 64 + d0 + 16] = hi;
        } else {
          Vtg[((size_t)bh * 64 + d0) * 2048 + n]        = lo;
          Vtg[((size_t)bh * 64 + d0 + 16) * 2048 + n]   = hi;
        }
      }
    }
  }
}

// ---------------------------------------------------------------------------
// Flash attention: swapped QK^T, no-max softmax, packed b64 P-store,
// swizzled LDS, counted-vmcnt dual-barrier staging (R7 form), XCD swizzle.
__global__ __launch_bounds__(256) void k_attn(const short* __restrict__ Qg,
                                              const short* __restrict__ Kg,
                                              const short* __restrict__ Vtg,
                                              short* __restrict__ aout) {
  __shared__ short KV[2][8192];     // [buf][ K: 0..4095 | V: 4096..8191 ]
  __shared__ short Ps[4][1024];     // per-wave [16 q][64 k], swizzled
  const int tid = threadIdx.x;
  const int w = tid >> 6, lane = tid & 63;
  const int lhi = lane >> 4, llo = lane & 15;
  const int rin = lane >> 3;               // 0..7: row within 8-row chunk
  const int tg = (lane & 7) ^ rin;         // pre-swizzled 16B slot in source

  // XCD swizzle: 1024 blocks = 8 XCDs x 128; XCD k owns bh in [4k, 4k+4)
  // so its K/V working set (4 x 512KB) is L2-resident.
  const int b = blockIdx.x;
  const int w2 = (b & 7) * 128 + (b >> 3);
  const int bh = w2 >> 5;
  const int qrow0 = (w2 & 31) * 64 + w * 16;

  const short* Qrow = Qg + ((size_t)bh * 2048 + qrow0 + llo) * 64;
  const bf16x8 qa0 = *(const bf16x8*)(Qrow + lhi * 8);
  const bf16x8 qa1 = *(const bf16x8*)(Qrow + 32 + lhi * 8);

  bf16x8 onesb;
#pragma unroll
  for (int e = 0; e < 8; e++) onesb[e] = (short)0x3F80;   // bf16 1.0

  const f32x4 fz = {0.f, 0.f, 0.f, 0.f};
  f32x4 o[4];
#pragma unroll
  for (int dg = 0; dg < 4; dg++) o[dg] = fz;
  f32x4 lsum = fz;

  short* Pw = Ps[w];
  const size_t kbase = (size_t)bh * 2048;
  const size_t vbase = (size_t)bh * 64;

  // staging pointers: waves 0,1 load K chunks (advance 64 rows * 64 = 4096),
  // waves 2,3 load V^T chunks (advance 64 cols = 64).
  const short* gp[4];
#pragma unroll
  for (int i = 0; i < 4; i++) {
    const int cc = w * 4 + i;
    gp[i] = (cc < 8)
        ? (Kg  + (kbase + (size_t)(cc * 8 + rin)) * 64 + tg * 8)
        : (Vtg + (vbase + (size_t)((cc - 8) * 8 + rin)) * 2048 + tg * 8);
  }
  const int gstride = (w < 2) ? 4096 : 64;

#define STAGE(buf)                                                             \
  {                                                                            \
    _Pragma("unroll")                                                          \
    for (int i = 0; i < 4; i++) {                                              \
      gld16(gp[i], &KV[buf][(w * 4 + i) * 512]);                               \
      gp[i] += gstride;                                                        \
    }                                                                          \
  }

  STAGE(0);
  int cur = 0;

  for (int kt = 0; kt < 32; kt++) {
    if (kt < 31) {
      STAGE(cur ^ 1);                             // 4 new loads in flight
      asm volatile("s_waitcnt vmcnt(4)" ::: "memory");   // stage(cur) done
    } else {
      asm volatile("s_waitcnt vmcnt(0)" ::: "memory");
    }
    __builtin_amdgcn_s_barrier();                 // all waves' stage done
    __builtin_amdgcn_sched_barrier(0);

    const short* Kc = KV[cur];
    const short* Vc = KV[cur] + 4096;

    // S^T[64 k x 16 q] = K @ Q^T  (swapped operands; frag layouts identical)
    // => lane holds S[q=llo][k = krg*16 + lhi*4 + j]
    f32x4 s[4];
    __builtin_amdgcn_s_setprio(1);
#pragma unroll
    for (int krg = 0; krg < 4; krg++) {
      const int rk = krg * 16 + llo;
      const int sw = rk & 7;
      const bf16x8 kb0 = *(const bf16x8*)(Kc + rk * 64 + ((lhi ^ sw)) * 8);
      const bf16x8 kb1 = *(const bf16x8*)(Kc + rk * 64 + (((4 + lhi) ^ sw)) * 8);
      f32x4 z = fz;
      z = __builtin_amdgcn_mfma_f32_16x16x32_bf16(kb0, qa0, z, 0, 0, 0);
      z = __builtin_amdgcn_mfma_f32_16x16x32_bf16(kb1, qa1, z, 0, 0, 0);
      s[krg] = z;
    }
    __builtin_amdgcn_s_setprio(0);

    // P = exp(S); pack 4 consecutive-k bf16 (RNE pk2), ds_write_b64 per krg.
#pragma unroll
    for (int krg = 0; krg < 4; krg++) {
      const float p0 = __expf(s[krg][0]);
      const float p1 = __expf(s[krg][1]);
      const float p2 = __expf(s[krg][2]);
      const float p3 = __expf(s[krg][3]);
      uint2 u;
      u.x = pk2(p0, p1);
      u.y = pk2(p2, p3);
      // byte addr: row llo, k = krg*16 + lhi*4 ; slot = k>>3, swizzled
      char* pb = (char*)Pw + llo * 128 +
                 (((krg * 2 + (lhi >> 1)) ^ (llo & 7)) << 4) + ((lhi & 1) << 3);
      *(uint2*)pb = u;
    }

    // P fragments (A-layout): row=llo, swizzle-read
    const int swp = llo & 7;
    const bf16x8 pa0 = *(const bf16x8*)(Pw + llo * 64 + ((lhi ^ swp)) * 8);
    const bf16x8 pa1 = *(const bf16x8*)(Pw + llo * 64 + (((4 + lhi) ^ swp)) * 8);

    __builtin_amdgcn_s_setprio(1);
    // row sums via MFMA with ones-B (each col of C gets the full row sum)
    lsum = __builtin_amdgcn_mfma_f32_16x16x32_bf16(pa0, onesb, lsum, 0, 0, 0);
    lsum = __builtin_amdgcn_mfma_f32_16x16x32_bf16(pa1, onesb, lsum, 0, 0, 0);

    // O += P @ V   (V^T tile, swizzle-read)
#pragma unroll
    for (int dg = 0; dg < 4; dg++) {
      const int rv = dg * 16 + llo;
      const int swv = rv & 7;
      const bf16x8 vb0 = *(const bf16x8*)(Vc + rv * 64 + ((lhi ^ swv)) * 8);
      const bf16x8 vb1 = *(const bf16x8*)(Vc + rv * 64 + (((4 + lhi) ^ swv)) * 8);
      o[dg] = __builtin_amdgcn_mfma_f32_16x16x32_bf16(pa0, vb0, o[dg], 0, 0, 0);
      o[dg] = __builtin_amdgcn_mfma_f32_16x16x32_bf16(pa1, vb1, o[dg], 0, 0, 0);
    }
    __builtin_amdgcn_s_setprio(0);
    __builtin_amdgcn_s_barrier();                 // reads of cur done
    cur ^= 1;
  }
#undef STAGE

  const int b_ = bh >> 4, h = bh & 15;
#pragma unroll
  for (int j = 0; j < 4; j++) {
    const float inv = 1.f / lsum[j];
    const int n = qrow0 + lhi * 4 + j;
    short* arow = aout + ((size_t)(b_ * 2048 + n)) * 1024 + h * 64 + llo;
#pragma unroll
    for (int dp = 0; dp < 2; dp++) {            // dg pairs (0,1), (2,3)
      const unsigned u = pk2(o[dp * 2][j] * inv, o[dp * 2 + 1][j] * inv);
      arow[dp * 32]      = (short)(u & 0xffffu);
      arow[dp * 32 + 16] = (short)(u >> 16);
    }
  }
}

// ---------------------------------------------------------------------------
// GEMM2: out = aout @ w_proj + b_proj  (fp32 output)
__global__ __launch_bounds__(256) void k_gemm_proj(const short* __restrict__ A,
                                                   const short* __restrict__ B,
                                                   const float* __restrict__ bias,
                                                   float* __restrict__ C) {
  __shared__ short As[2 * 8192];
  __shared__ short Bs[2 * 8192];
  f32x4 acc[4][4];
  const int mBase = blockIdx.x * 128, nBase = blockIdx.y * 128;
  mm_loop(A, B, 1024, mBase, nBase, As, Bs, acc);

  const int tid = threadIdx.x;
  const int w = tid >> 6, lane = tid & 63;
  const int wr = w >> 1, wc = w & 1;
  const int lhi = lane >> 4, llo = lane & 15;
#pragma unroll
  for (int mi = 0; mi < 4; mi++)
#pragma unroll
    for (int ni = 0; ni < 4; ni++) {
      const int col = nBase + wc * 64 + ni * 16 + llo;
      const float bv = bias[col];
#pragma unroll
      for (int j = 0; j < 4; j++) {
        const int row = mBase + wr * 64 + mi * 16 + lhi * 4 + j;
        C[(size_t)row * 1024 + col] = acc[mi][ni][j] + bv;
      }
    }
}

// ---------------------------------------------------------------------------
extern "C" void kernel_launch(void* const* d_in, const int* in_sizes, int n_in,
                              void* d_out, int out_size, void* d_ws, size_t ws_size,
                              hipStream_t stream) {
  const float* x      = (const float*)d_in[0];
  const float* w_qkv  = (const float*)d_in[1];
  const float* b_qkv  = (const float*)d_in[2];
  const float* g_q    = (const float*)d_in[3];
  const float* be_q   = (const float*)d_in[4];
  const float* g_k    = (const float*)d_in[5];
  const float* be_k   = (const float*)d_in[6];
  const float* w_proj = (const float*)d_in[7];
  const float* b_proj = (const float*)d_in[8];
  float* out = (float*)d_out;

  char* ws = (char*)d_ws;
  short* xb     = (short*)(ws);                       // 4096x1024      8 MB
  short* wqkvT  = (short*)(ws + ((size_t)8  << 20));  // 3072x1024      6 MB
  short* wprojT = (short*)(ws + ((size_t)14 << 20));  // 1024x1024      2 MB
  short* Qg     = (short*)(ws + ((size_t)16 << 20));  // [32][2048][64] 8 MB
  short* Kg     = (short*)(ws + ((size_t)24 << 20));  // [32][2048][64] 8 MB
  short* Vtg    = (short*)(ws + ((size_t)32 << 20));  // [32][64][2048] 8 MB
  short* aout   = (short*)(ws + ((size_t)40 << 20));  // 4096x1024      8 MB

  k_cvt<<<4096, 256, 0, stream>>>(x, xb, 4096 * 1024);
  k_transpose<<<dim3(3072 / 32, 1024 / 32), dim3(32, 8), 0, stream>>>(w_qkv, wqkvT, 1024, 3072);
  k_transpose<<<dim3(1024 / 32, 1024 / 32), dim3(32, 8), 0, stream>>>(w_proj, wprojT, 1024, 1024);
  k_gemm_qkv<<<dim3(32, 24), 256, 0, stream>>>(xb, wqkvT, b_qkv, g_q, be_q, g_k, be_k, Qg, Kg, Vtg);
  k_attn<<<1024, 256, 0, stream>>>(Qg, Kg, Vtg, aout);
  k_gemm_proj<<<dim3(32, 8), 256, 0, stream>>>(aout, wprojT, b_proj, out);
}